// Round 10
// baseline (106.873 us; speedup 1.0000x reference)
//
#include <hip/hip_runtime.h>
#include <hip/hip_bf16.h>

// out = X + s*(relu(A_hat @ (X @ W_agg)) - X), s = sigmoid(wg)*sigmoid(wl)
// X[8192,256] f32, A_hat[8192,8192] f32, W[256,256] f32. Out f32 [8192,256].
// Round 10: overlap. r9 model validated zero port-overlap (serial sum == observed).
// (1) BK=64 barrier periods (16 vs 32): half the barriers, double the interleave
// window; B-frag loads split across the period. (2) s_sleep anti-phase stagger for
// the co-resident block pair (bid, bid+256) to break the vmem/LDS convoy.

typedef __attribute__((ext_vector_type(4))) float f32x4;
typedef __attribute__((ext_vector_type(8))) __bf16 bf16x8;
typedef __attribute__((ext_vector_type(8))) unsigned short u16x8;

#define GLOBAL_AS __attribute__((address_space(1)))
#define LDS_AS __attribute__((address_space(3)))

static __device__ __forceinline__ void gload16(const void* g, void* l) {
  __builtin_amdgcn_global_load_lds((const GLOBAL_AS void*)g, (LDS_AS void*)l, 16, 0, 0);
}
static __device__ __forceinline__ void gload16_stream(const void* g, void* l) {
  __builtin_amdgcn_global_load_lds((const GLOBAL_AS void*)g, (LDS_AS void*)l, 16, 0, 0x12);
}

static __device__ __forceinline__ unsigned short f2bf_bits(float f) {
  __bf16 h = (__bf16)f;
  return __builtin_bit_cast(unsigned short, h);
}
static __device__ __forceinline__ float bf2f(unsigned short u) {
  return __builtin_bit_cast(float, (unsigned)u << 16);
}

// ---------------- prep: s vector + W^T (bf16, tiled [k/32][n=256][32]) -------------
__global__ void prep_kernel(const float* __restrict__ W,
                            const float* __restrict__ wg,
                            const float* __restrict__ wl,
                            unsigned short* __restrict__ WT,  // [8][256][32] bf16
                            float* __restrict__ s) {
  int tid = blockIdx.x * 256 + threadIdx.x;  // 0..65535
  int k = tid >> 8, n = tid & 255;
  float w = W[tid];  // W[k][n]
  int kt = k >> 5, kloc = k & 31;
  WT[kt * 8192 + n * 32 + kloc] = f2bf_bits(w);
  if (tid < 8192) {
    float sg = 1.0f / (1.0f + expf(-wg[0]));
    float sl = 1.0f / (1.0f + expf(-wl[tid]));
    s[tid] = sg * sl;
  }
}

// ---------------- gemm0: XW = X @ W  ->  XWT2 in MFMA B-frag layout ----------------
// XWT2 block for (c=k/64, wp=n/32, kk=(k>>5)&1, ni=(n>>4)&1): 64 lanes x 16B, lane
// = (n&15) + 16*((k>>3)&3), holding 8 consecutive bf16 along k.
__global__ __launch_bounds__(256, 2) void gemm_xw(
    const float* __restrict__ X,              // [8192][256]
    const unsigned short* __restrict__ WT,    // tiled [8][256][32]
    unsigned short* __restrict__ XWT2) {      // 4 MiB, frag-layout
  __shared__ float As[2][32 * 32];
  __shared__ unsigned short Bs[2][128 * 32];

  const int bm = blockIdx.x & 255;
  const int bn = blockIdx.x >> 8;
  const int m0 = bm * 32;
  const int tid = threadIdx.x;
  const int w = tid >> 6;
  const int l = tid & 63;
  const int lr = l & 15;
  const int lq = l >> 4;

  const int pA = w * 1024 + l * 16;
  const int rA = pA >> 7;
  const int qA = (pA >> 4) & 7;
  const int ssA = qA ^ (rA & 7);
  const char* Asrc0 = (const char*)X + (size_t)(m0 + rA) * 1024 + ssA * 16;
  const char* Bsrc0 = (const char*)WT + bn * 8192 + w * 2048 + l * 16;

  f32x4 acc[2][2];
#pragma unroll
  for (int i = 0; i < 2; ++i)
#pragma unroll
    for (int j = 0; j < 2; ++j) acc[i][j] = (f32x4){0.f, 0.f, 0.f, 0.f};

  auto stage = [&](int t, int buf) {
    gload16(Asrc0 + (size_t)t * 128, (char*)&As[buf][0] + w * 1024);
    const char* bs = Bsrc0 + (size_t)t * 16384;
    gload16(bs, (char*)&Bs[buf][0] + w * 2048);
    gload16(bs + 1024, (char*)&Bs[buf][0] + w * 2048 + 1024);
  };

  auto compute = [&](int buf) {
    bf16x8 af[2];
#pragma unroll
    for (int mi = 0; mi < 2; ++mi) {
      int r = mi * 16 + lr;
      const float* ap = &As[buf][r * 32];
      int s0 = (2 * lq) ^ (r & 7);
      int s1 = (2 * lq + 1) ^ (r & 7);
      f32x4 a0 = *(const f32x4*)(ap + s0 * 4);
      f32x4 a1 = *(const f32x4*)(ap + s1 * 4);
      bf16x8 v;
      v[0] = (__bf16)a0.x; v[1] = (__bf16)a0.y; v[2] = (__bf16)a0.z; v[3] = (__bf16)a0.w;
      v[4] = (__bf16)a1.x; v[5] = (__bf16)a1.y; v[6] = (__bf16)a1.z; v[7] = (__bf16)a1.w;
      af[mi] = v;
    }
    bf16x8 bfr[2];
#pragma unroll
    for (int ni = 0; ni < 2; ++ni) {
      int row = w * 32 + ni * 16 + lr;
      bfr[ni] = *(const bf16x8*)(&Bs[buf][row * 32 + lq * 8]);
    }
#pragma unroll
    for (int mi = 0; mi < 2; ++mi)
#pragma unroll
      for (int ni = 0; ni < 2; ++ni)
        acc[mi][ni] = __builtin_amdgcn_mfma_f32_16x16x32_bf16(af[mi], bfr[ni], acc[mi][ni], 0, 0, 0);
  };

  stage(0, 0);
  __syncthreads();
  for (int t = 0; t < 8; ++t) {
    int cur = t & 1;
    if (t + 1 < 8) stage(t + 1, cur ^ 1);
    compute(cur);
    __syncthreads();
  }

  // epilogue -> XWT2 frag layout. k (main-GEMM contraction) = bm*32 + mi*16 + lq*4
#pragma unroll
  for (int mi = 0; mi < 2; ++mi)
#pragma unroll
    for (int ni2 = 0; ni2 < 2; ++ni2) {
      f32x4 z = acc[mi][ni2];
      int n = bn * 128 + w * 32 + ni2 * 16 + lr;
      int k = bm * 32 + mi * 16 + lq * 4;
      int c = k >> 6;
      int kk = (k >> 5) & 1;
      int ni = (n >> 4) & 1;
      int wp = n >> 5;
      int lane2 = (n & 15) + 16 * ((k >> 3) & 3);
      int j0 = k & 7;  // 0 or 4
      size_t off = (((size_t)c * 8 + wp) * 4 + kk * 2 + ni) * 512 + lane2 * 8 + j0;
      ushort4 u;
      u.x = f2bf_bits(z[0]); u.y = f2bf_bits(z[1]);
      u.z = f2bf_bits(z[2]); u.w = f2bf_bits(z[3]);
      *(ushort4*)(XWT2 + off) = u;
    }
}

// ---------------- gemm_ks8: P[kseg] = A[:, kseg] @ XW[kseg]  (bf16 partials) -------
// BM=128, BN=256, BK=64 per barrier period (16 periods), ksplit=8. Grid 512 =
// 2 blocks/CU, 512 thr = 8 waves, wave w owns n-strip w*32 (no B duplication).
// A reg-staged f32->bf16 into frag-major LDS [buf][ks][mi][fl] (lane-linear
// ds_read, free). Co-resident pair (bid, bid+256) staggered ~1/3 period via
// s_sleep to break the vmem/LDS phase convoy.
__global__ __launch_bounds__(512, 4) void gemm_ks8(
    const float* __restrict__ A,              // [8192][8192]
    const unsigned short* __restrict__ B2,    // XWT2 frag layout
    unsigned short* __restrict__ P) {         // [8][8192][256] bf16 partials
  __shared__ unsigned short Al[2][16 * 512];  // 2 x 16KB: [ks(2)][mi(8)][fl(64)][8]

  const int bid = blockIdx.x;
  const int mtile = bid >> 3, kseg = bid & 7;  // kseg == XCD id (round-robin)
  const int m0 = mtile * 128;
  const int tid = threadIdx.x;  // 0..511
  const int w = tid >> 6, l = tid & 63;
  const int lr = l & 15, lq = l >> 4;

  if (bid & 256) __builtin_amdgcn_s_sleep(32);  // ~2048 cyc anti-phase stagger

  // staging: thread t -> A row r=t>>2, 16 consecutive floats at col (t&3)*16
  // within the 64k period. Dest: sub-step ks=(t&3)>>1, frag mi=r>>4, slots
  // kq0=((t&3)&1)*2 and kq0+1 (frag-lane fl = (r&15)+16*kq).
  const int r = tid >> 2, c4 = tid & 3;
  const float* gA = A + (size_t)(m0 + r) * 8192 + kseg * 1024 + c4 * 16;
  const int ks = c4 >> 1, kq0 = (c4 & 1) * 2;
  const int woff0 = (ks * 8 + (r >> 4)) * 512 + ((r & 15) + 16 * kq0) * 8;

  const unsigned short* Bbase = B2 + (size_t)kseg * 262144 + l * 8;

  f32x4 acc[8][2];
#pragma unroll
  for (int i = 0; i < 8; ++i)
#pragma unroll
    for (int j = 0; j < 2; ++j) acc[i][j] = (f32x4){0.f, 0.f, 0.f, 0.f};

  f32x4 sa0, sa1, sa2, sa3;       // staged A (16 floats)
  bf16x8 BfA0, BfA1, BfB0, BfB1;  // B frags for the two 32k halves

  auto loadA = [&](int h) {  // h = period (64 floats along k)
    const float* p = gA + h * 64;
    sa0 = *(const f32x4*)(p);
    sa1 = *(const f32x4*)(p + 4);
    sa2 = *(const f32x4*)(p + 8);
    sa3 = *(const f32x4*)(p + 12);
  };
  auto writeA = [&](int h) {  // cvt + 2x ds_write into Al[h&1]
    bf16x8 b0, b1;
    b0[0] = (__bf16)sa0.x; b0[1] = (__bf16)sa0.y; b0[2] = (__bf16)sa0.z; b0[3] = (__bf16)sa0.w;
    b0[4] = (__bf16)sa1.x; b0[5] = (__bf16)sa1.y; b0[6] = (__bf16)sa1.z; b0[7] = (__bf16)sa1.w;
    b1[0] = (__bf16)sa2.x; b1[1] = (__bf16)sa2.y; b1[2] = (__bf16)sa2.z; b1[3] = (__bf16)sa2.w;
    b1[4] = (__bf16)sa3.x; b1[5] = (__bf16)sa3.y; b1[6] = (__bf16)sa3.z; b1[7] = (__bf16)sa3.w;
    *(bf16x8*)(&Al[h & 1][woff0]) = b0;
    *(bf16x8*)(&Al[h & 1][woff0 + 128]) = b1;  // kq0+1 slot
  };
  auto loadBA = [&](int h) {  // kstep 2h: c=h, kk=0
    const unsigned short* p = Bbase + (((h * 8 + w) * 4 + 0) << 9);
    BfA0 = *(const bf16x8*)(p);
    BfA1 = *(const bf16x8*)(p + 512);
  };
  auto loadBB = [&](int h) {  // kstep 2h+1: c=h, kk=1
    const unsigned short* p = Bbase + (((h * 8 + w) * 4 + 2) << 9);
    BfB0 = *(const bf16x8*)(p);
    BfB1 = *(const bf16x8*)(p + 512);
  };
  auto computeHalf = [&](int buf, int ksel, const bf16x8& F0, const bf16x8& F1) {
    const unsigned short* Ab = &Al[buf][ksel * 4096];
#pragma unroll
    for (int mi = 0; mi < 8; ++mi) {
      bf16x8 af = *(const bf16x8*)(Ab + mi * 512 + l * 8);  // lane-linear
      acc[mi][0] = __builtin_amdgcn_mfma_f32_16x16x32_bf16(af, F0, acc[mi][0], 0, 0, 0);
      acc[mi][1] = __builtin_amdgcn_mfma_f32_16x16x32_bf16(af, F1, acc[mi][1], 0, 0, 0);
    }
  };

  // prologue: A(0) staged+written; B(0) halves + A(1) in flight
  loadA(0);
  writeA(0);
  loadBA(0);
  loadBB(0);
  loadA(1);
  asm volatile("s_waitcnt lgkmcnt(0)" ::: "memory");
  asm volatile("s_barrier" ::: "memory");

  for (int h = 0; h < 15; ++h) {
    computeHalf(h & 1, 0, BfA0, BfA1);
    loadBA(h + 1);
    computeHalf(h & 1, 1, BfB0, BfB1);
    loadBB(h + 1);
    writeA(h + 1);  // compiler-counted vmcnt wait on sa(h+1)
    if (h < 14) loadA(h + 2);
    asm volatile("s_waitcnt lgkmcnt(0)" ::: "memory");
    asm volatile("s_barrier" ::: "memory");
  }
  computeHalf(1, 0, BfA0, BfA1);  // period 15
  computeHalf(1, 1, BfB0, BfB1);

  // epilogue: bf16 partial P[kseg][m][n]
  unsigned short* Pb = P + (size_t)kseg * (8192 * 256);
#pragma unroll
  for (int mi = 0; mi < 8; ++mi)
#pragma unroll
    for (int ni = 0; ni < 2; ++ni) {
      f32x4 z = acc[mi][ni];
      int n = w * 32 + ni * 16 + lr;
#pragma unroll
      for (int i = 0; i < 4; ++i) {
        int m = m0 + mi * 16 + lq * 4 + i;
        Pb[(size_t)m * 256 + n] = f2bf_bits(z[i]);
      }
    }
}

// ---------------- finalize8: out = x + s*(relu(sum P) - x) -------------------------
__global__ __launch_bounds__(256) void finalize8(
    const unsigned short* __restrict__ P,   // [8][8192][256] bf16
    const float* __restrict__ X,
    const float* __restrict__ s,
    float* __restrict__ out) {
  int i = blockIdx.x * 256 + threadIdx.x;  // 0..262143, 8 n-values each
  int m = i >> 5;
  float acc[8] = {0.f, 0.f, 0.f, 0.f, 0.f, 0.f, 0.f, 0.f};
#pragma unroll
  for (int ks = 0; ks < 8; ++ks) {
    u16x8 v = *(const u16x8*)(P + (size_t)ks * 2097152 + (size_t)i * 8);
#pragma unroll
    for (int j = 0; j < 8; ++j) acc[j] += bf2f(v[j]);
  }
  float sv = s[m];
  f32x4 x0 = *(const f32x4*)(X + (size_t)i * 8);
  f32x4 x1 = *(const f32x4*)(X + (size_t)i * 8 + 4);
  f32x4 o0, o1;
#pragma unroll
  for (int j = 0; j < 4; ++j) {
    o0[j] = x0[j] + sv * (fmaxf(acc[j], 0.f) - x0[j]);
    o1[j] = x1[j] + sv * (fmaxf(acc[4 + j], 0.f) - x1[j]);
  }
  *(f32x4*)(out + (size_t)i * 8) = o0;
  *(f32x4*)(out + (size_t)i * 8 + 4) = o1;
}

// ================= fallback path (round-6 kernels, unchanged) ======================
template <int NT, bool SPLIT>
__global__ __launch_bounds__(512, 4) void gemm_main(
    const float* __restrict__ A,
    const unsigned short* __restrict__ B2,
    const float* __restrict__ X,
    const float* __restrict__ s,
    float* __restrict__ out,
    float* __restrict__ P) {
  __shared__ float As[4][32 * 64];

  const int bid = blockIdx.x;
  const int m0 = SPLIT ? (bid >> 1) * 32 : bid * 32;
  const int khalf = SPLIT ? (bid & 1) : 0;
  const int tid = threadIdx.x;
  const int w = tid >> 6;
  const int l = tid & 63;
  const int lr = l & 15;
  const int lq = l >> 4;

  const int rA = tid >> 4;
  const int qA = tid & 15;
  const int sqA = qA ^ (rA & 15);
  const char* Asrc =
      (const char*)A + (size_t)(m0 + rA) * 32768 + (size_t)khalf * 16384 + sqA * 16;
  const char* Bbase =
      (const char*)B2 + (size_t)khalf * 64 * 32768 + (size_t)w * 4096 + (size_t)l * 16;

  f32x4 acc[2][2];
#pragma unroll
  for (int i = 0; i < 2; ++i)
#pragma unroll
    for (int j = 0; j < 2; ++j) acc[i][j] = (f32x4){0.f, 0.f, 0.f, 0.f};

  struct BF { bf16x8 a, b, c, d; };
  BF Bf0, Bf1;

  auto stageA = [&](int h, int buf) {
    gload16_stream(Asrc + (size_t)h * 256, (char*)&As[buf][0] + w * 1024);
  };
  auto loadB = [&](int h, BF& f) {
    const char* p = Bbase + (size_t)h * 32768;
    f.a = *(const bf16x8*)(p);
    f.b = *(const bf16x8*)(p + 1024);
    f.c = *(const bf16x8*)(p + 2048);
    f.d = *(const bf16x8*)(p + 3072);
  };

  auto compute = [&](int buf, const BF& f) {
    const char* Ab = (const char*)&As[buf][0];
    bf16x8 af[2][2];
#pragma unroll
    for (int kk = 0; kk < 2; ++kk)
#pragma unroll
      for (int mi = 0; mi < 2; ++mi) {
        int rr = mi * 16 + lr;
        int s0 = (kk * 8 + 2 * lq) ^ (rr & 15);
        int s1 = ((kk * 8 + 2 * lq) + 1) ^ (rr & 15);
        f32x4 a0 = *(const f32x4*)(Ab + rr * 256 + s0 * 16);
        f32x4 a1 = *(const f32x4*)(Ab + rr * 256 + s1 * 16);
        bf16x8 v;
        v[0] = (__bf16)a0.x; v[1] = (__bf16)a0.y; v[2] = (__bf16)a0.z; v[3] = (__bf16)a0.w;
        v[4] = (__bf16)a1.x; v[5] = (__bf16)a1.y; v[6] = (__bf16)a1.z; v[7] = (__bf16)a1.w;
        af[kk][mi] = v;
      }
    acc[0][0] = __builtin_amdgcn_mfma_f32_16x16x32_bf16(af[0][0], f.a, acc[0][0], 0, 0, 0);
    acc[0][1] = __builtin_amdgcn_mfma_f32_16x16x32_bf16(af[0][0], f.b, acc[0][1], 0, 0, 0);
    acc[1][0] = __builtin_amdgcn_mfma_f32_16x16x32_bf16(af[0][1], f.a, acc[1][0], 0, 0, 0);
    acc[1][1] = __builtin_amdgcn_mfma_f32_16x16x32_bf16(af[0][1], f.b, acc[1][1], 0, 0, 0);
    acc[0][0] = __builtin_amdgcn_mfma_f32_16x16x32_bf16(af[1][0], f.c, acc[0][0], 0, 0, 0);
    acc[0][1] = __builtin_amdgcn_mfma_f32_16x16x32_bf16(af[1][0], f.d, acc[0][1], 0, 0, 0);
    acc[1][0] = __builtin_amdgcn_mfma_f32_16x16x32_bf16(af[1][1], f.c, acc[1][0], 0, 0, 0);
    acc[1][1] = __builtin_amdgcn_mfma_f32_16x16x32_bf16(af[1][1], f.d, acc[1][1], 0, 0, 0);
  };

  stageA(0, 0);
  loadB(0, Bf0);
  stageA(1, 1);
  loadB(1, Bf1);
  stageA(2, 2);
  stageA(3, 3);

  for (int h = 0; h < NT - 4; h += 2) {
    asm volatile("s_waitcnt vmcnt(6)" ::: "memory");
    asm volatile("s_barrier" ::: "memory");
    compute(h & 3, Bf0);
    asm volatile("s_waitcnt lgkmcnt(0)" ::: "memory");
    asm volatile("s_barrier" ::: "memory");
    loadB(h + 2, Bf0);
    stageA(h + 4, h & 3);

    asm volatile("s_waitcnt vmcnt(6)" ::: "memory");
    asm volatile("s_barrier" ::: "memory");
    compute((h + 1) & 3, Bf1);
    asm volatile("s_waitcnt lgkmcnt(0)" ::: "memory");
    asm volatile("s_barrier" ::: "memory");
    loadB(h + 3, Bf1);
    stageA(h + 5, (h + 1) & 3);
  }
  asm volatile("s_waitcnt vmcnt(6)" ::: "memory");
  asm volatile("s_barrier" ::: "memory");
  compute(0, Bf0);
  asm volatile("s_waitcnt lgkmcnt(0)" ::: "memory");
  asm volatile("s_barrier" ::: "memory");
  loadB(NT - 2, Bf0);

  asm volatile("s_waitcnt vmcnt(5)" ::: "memory");
  asm volatile("s_barrier" ::: "memory");
  compute(1, Bf1);
  asm volatile("s_waitcnt lgkmcnt(0)" ::: "memory");
  asm volatile("s_barrier" ::: "memory");
  loadB(NT - 1, Bf1);

  asm volatile("s_waitcnt vmcnt(4)" ::: "memory");
  asm volatile("s_barrier" ::: "memory");
  compute(2, Bf0);
  asm volatile("s_waitcnt lgkmcnt(0)" ::: "memory");
  asm volatile("s_barrier" ::: "memory");

  asm volatile("s_waitcnt vmcnt(0)" ::: "memory");
  asm volatile("s_barrier" ::: "memory");
  compute(3, Bf1);

  if (SPLIT) {
    float* Pb = P + (size_t)khalf * 8192 * 256;
#pragma unroll
    for (int mi = 0; mi < 2; ++mi)
#pragma unroll
      for (int ni = 0; ni < 2; ++ni) {
        f32x4 z = acc[mi][ni];
        int n = w * 32 + ni * 16 + lr;
#pragma unroll
        for (int i = 0; i < 4; ++i) {
          int m = m0 + mi * 16 + lq * 4 + i;
          Pb[m * 256 + n] = z[i];
        }
      }
  } else {
#pragma unroll
    for (int mi = 0; mi < 2; ++mi)
#pragma unroll
      for (int ni = 0; ni < 2; ++ni) {
        f32x4 z = acc[mi][ni];
        int n = w * 32 + ni * 16 + lr;
#pragma unroll
        for (int i = 0; i < 4; ++i) {
          int m = m0 + mi * 16 + lq * 4 + i;
          float x = X[m * 256 + n];
          float sv = s[m];
          out[m * 256 + n] = x + sv * (fmaxf(z[i], 0.f) - x);
        }
      }
  }
}

__global__ __launch_bounds__(256) void finalize_kernel(
    const float* __restrict__ P,
    const float* __restrict__ X,
    const float* __restrict__ s,
    float* __restrict__ out) {
  int i = blockIdx.x * 256 + threadIdx.x;
  int m = i >> 6;
  f32x4 p0 = *(const f32x4*)(P + (size_t)i * 4);
  f32x4 p1 = *(const f32x4*)(P + 2097152 + (size_t)i * 4);
  f32x4 x = *(const f32x4*)(X + (size_t)i * 4);
  float sv = s[m];
  f32x4 o;
#pragma unroll
  for (int j = 0; j < 4; ++j) o[j] = x[j] + sv * (fmaxf(p0[j] + p1[j], 0.f) - x[j]);
  *(f32x4*)(out + (size_t)i * 4) = o;
}

extern "C" void kernel_launch(void* const* d_in, const int* in_sizes, int n_in,
                              void* d_out, int out_size, void* d_ws, size_t ws_size,
                              hipStream_t stream) {
  const float* X = (const float*)d_in[0];
  const float* A = (const float*)d_in[1];
  const float* wg = (const float*)d_in[2];
  const float* wl = (const float*)d_in[3];
  const float* W = (const float*)d_in[4];
  float* out = (float*)d_out;

  // ws: XWT2 4 MiB | WT 128 KiB | s 32 KiB | P (bf16 32 MiB new / f32 16 MiB old)
  unsigned short* XWT2 = (unsigned short*)d_ws;
  unsigned short* WT = (unsigned short*)((char*)d_ws + 4194304);
  float* s = (float*)((char*)d_ws + 4194304 + 131072);
  char* Pbase = (char*)d_ws + 4194304 + 131072 + 32768;

  prep_kernel<<<256, 256, 0, stream>>>(W, wg, wl, WT, s);
  gemm_xw<<<512, 256, 0, stream>>>(X, WT, XWT2);

  const size_t head = 4194304 + 131072 + 32768;
  const size_t need8 = head + (size_t)8 * 8192 * 256 * 2;   // bf16 partials
  const size_t need2 = head + (size_t)2 * 8192 * 256 * 4;   // f32 partials
  if (ws_size >= need8) {
    gemm_ks8<<<512, 512, 0, stream>>>(A, XWT2, (unsigned short*)Pbase);
    finalize8<<<1024, 256, 0, stream>>>((const unsigned short*)Pbase, X, s, out);
  } else if (ws_size >= need2) {
    gemm_main<64, true><<<512, 512, 0, stream>>>(A, XWT2, X, s, out, (float*)Pbase);
    finalize_kernel<<<2048, 256, 0, stream>>>((const float*)Pbase, X, s, out);
  } else {
    gemm_main<128, false><<<256, 512, 0, stream>>>(A, XWT2, X, s, out, nullptr);
  }
}

// Round 11
// 100.648 us; speedup vs baseline: 1.0618x; 1.0618x over previous
//
#include <hip/hip_runtime.h>
#include <hip/hip_bf16.h>

// out = X + s*(relu(A_hat @ (X @ W_agg)) - X), s = sigmoid(wg)*sigmoid(wl)
// X[8192,256] f32, A_hat[8192,8192] f32, W[256,256] f32. Out f32 [8192,256].
// Round 11: r9 skeleton (best, 103.4us) + issue-early pipeline: A loads
// double-buffered in registers (saE/saO) and issued at the TOP of each period,
// so ~18KB/block stays in flight through compute (r9 time-avg was ~9KB ->
// 13GB/s/CU latency-starved; target = 24.6GB/s/CU fair share).

typedef __attribute__((ext_vector_type(4))) float f32x4;
typedef __attribute__((ext_vector_type(8))) __bf16 bf16x8;
typedef __attribute__((ext_vector_type(8))) unsigned short u16x8;

#define GLOBAL_AS __attribute__((address_space(1)))
#define LDS_AS __attribute__((address_space(3)))

static __device__ __forceinline__ void gload16(const void* g, void* l) {
  __builtin_amdgcn_global_load_lds((const GLOBAL_AS void*)g, (LDS_AS void*)l, 16, 0, 0);
}
static __device__ __forceinline__ void gload16_stream(const void* g, void* l) {
  __builtin_amdgcn_global_load_lds((const GLOBAL_AS void*)g, (LDS_AS void*)l, 16, 0, 0x12);
}

static __device__ __forceinline__ unsigned short f2bf_bits(float f) {
  __bf16 h = (__bf16)f;
  return __builtin_bit_cast(unsigned short, h);
}
static __device__ __forceinline__ float bf2f(unsigned short u) {
  return __builtin_bit_cast(float, (unsigned)u << 16);
}

// ---------------- prep: s vector + W^T (bf16, tiled [k/32][n=256][32]) -------------
__global__ void prep_kernel(const float* __restrict__ W,
                            const float* __restrict__ wg,
                            const float* __restrict__ wl,
                            unsigned short* __restrict__ WT,  // [8][256][32] bf16
                            float* __restrict__ s) {
  int tid = blockIdx.x * 256 + threadIdx.x;  // 0..65535
  int k = tid >> 8, n = tid & 255;
  float w = W[tid];  // W[k][n]
  int kt = k >> 5, kloc = k & 31;
  WT[kt * 8192 + n * 32 + kloc] = f2bf_bits(w);
  if (tid < 8192) {
    float sg = 1.0f / (1.0f + expf(-wg[0]));
    float sl = 1.0f / (1.0f + expf(-wl[tid]));
    s[tid] = sg * sl;
  }
}

// ---------------- gemm0: XW = X @ W  ->  XWT2 in MFMA B-frag layout ----------------
// XWT2 block for (c=k/64, wp=n/32, kk=(k>>5)&1, ni=(n>>4)&1): 64 lanes x 16B, lane
// = (n&15) + 16*((k>>3)&3), holding 8 consecutive bf16 along k.
__global__ __launch_bounds__(256, 2) void gemm_xw(
    const float* __restrict__ X,              // [8192][256]
    const unsigned short* __restrict__ WT,    // tiled [8][256][32]
    unsigned short* __restrict__ XWT2) {      // 4 MiB, frag-layout
  __shared__ float As[2][32 * 32];
  __shared__ unsigned short Bs[2][128 * 32];

  const int bm = blockIdx.x & 255;
  const int bn = blockIdx.x >> 8;
  const int m0 = bm * 32;
  const int tid = threadIdx.x;
  const int w = tid >> 6;
  const int l = tid & 63;
  const int lr = l & 15;
  const int lq = l >> 4;

  const int pA = w * 1024 + l * 16;
  const int rA = pA >> 7;
  const int qA = (pA >> 4) & 7;
  const int ssA = qA ^ (rA & 7);
  const char* Asrc0 = (const char*)X + (size_t)(m0 + rA) * 1024 + ssA * 16;
  const char* Bsrc0 = (const char*)WT + bn * 8192 + w * 2048 + l * 16;

  f32x4 acc[2][2];
#pragma unroll
  for (int i = 0; i < 2; ++i)
#pragma unroll
    for (int j = 0; j < 2; ++j) acc[i][j] = (f32x4){0.f, 0.f, 0.f, 0.f};

  auto stage = [&](int t, int buf) {
    gload16(Asrc0 + (size_t)t * 128, (char*)&As[buf][0] + w * 1024);
    const char* bs = Bsrc0 + (size_t)t * 16384;
    gload16(bs, (char*)&Bs[buf][0] + w * 2048);
    gload16(bs + 1024, (char*)&Bs[buf][0] + w * 2048 + 1024);
  };

  auto compute = [&](int buf) {
    bf16x8 af[2];
#pragma unroll
    for (int mi = 0; mi < 2; ++mi) {
      int r = mi * 16 + lr;
      const float* ap = &As[buf][r * 32];
      int s0 = (2 * lq) ^ (r & 7);
      int s1 = (2 * lq + 1) ^ (r & 7);
      f32x4 a0 = *(const f32x4*)(ap + s0 * 4);
      f32x4 a1 = *(const f32x4*)(ap + s1 * 4);
      bf16x8 v;
      v[0] = (__bf16)a0.x; v[1] = (__bf16)a0.y; v[2] = (__bf16)a0.z; v[3] = (__bf16)a0.w;
      v[4] = (__bf16)a1.x; v[5] = (__bf16)a1.y; v[6] = (__bf16)a1.z; v[7] = (__bf16)a1.w;
      af[mi] = v;
    }
    bf16x8 bfr[2];
#pragma unroll
    for (int ni = 0; ni < 2; ++ni) {
      int row = w * 32 + ni * 16 + lr;
      bfr[ni] = *(const bf16x8*)(&Bs[buf][row * 32 + lq * 8]);
    }
#pragma unroll
    for (int mi = 0; mi < 2; ++mi)
#pragma unroll
      for (int ni = 0; ni < 2; ++ni)
        acc[mi][ni] = __builtin_amdgcn_mfma_f32_16x16x32_bf16(af[mi], bfr[ni], acc[mi][ni], 0, 0, 0);
  };

  stage(0, 0);
  __syncthreads();
  for (int t = 0; t < 8; ++t) {
    int cur = t & 1;
    if (t + 1 < 8) stage(t + 1, cur ^ 1);
    compute(cur);
    __syncthreads();
  }

  // epilogue -> XWT2 frag layout. k (main-GEMM contraction) = bm*32 + mi*16 + lq*4
#pragma unroll
  for (int mi = 0; mi < 2; ++mi)
#pragma unroll
    for (int ni2 = 0; ni2 < 2; ++ni2) {
      f32x4 z = acc[mi][ni2];
      int n = bn * 128 + w * 32 + ni2 * 16 + lr;
      int k = bm * 32 + mi * 16 + lq * 4;
      int c = k >> 6;
      int kk = (k >> 5) & 1;
      int ni = (n >> 4) & 1;
      int wp = n >> 5;
      int lane2 = (n & 15) + 16 * ((k >> 3) & 3);
      int j0 = k & 7;  // 0 or 4
      size_t off = (((size_t)c * 8 + wp) * 4 + kk * 2 + ni) * 512 + lane2 * 8 + j0;
      ushort4 u;
      u.x = f2bf_bits(z[0]); u.y = f2bf_bits(z[1]);
      u.z = f2bf_bits(z[2]); u.w = f2bf_bits(z[3]);
      *(ushort4*)(XWT2 + off) = u;
    }
}

// ---------------- gemm_ks8: P[kseg] = A[:, kseg] @ XW[kseg]  (bf16 partials) -------
// BM=128, BN=256, BK=32, ksplit=8. Grid 512 = 2 blocks/CU, 512 thr = 8 waves,
// wave w owns n-strip w*32 (no B duplication). A reg-staged f32->bf16 into
// frag-major linear LDS (lane-linear ds_read, free). Issue-early 2-deep sa
// double-buffer: loads at period top, ~18KB/block in flight through compute.
__global__ __launch_bounds__(512, 4) void gemm_ks8(
    const float* __restrict__ A,              // [8192][8192]
    const unsigned short* __restrict__ B2,    // XWT2 frag layout
    unsigned short* __restrict__ P) {         // [8][8192][256] bf16 partials
  __shared__ unsigned short Al[2][8 * 512];   // 2 x 8KB: [mi][fl][8bf16]

  const int bid = blockIdx.x;
  const int mtile = bid >> 3, kseg = bid & 7;  // kseg == XCD id (round-robin)
  const int m0 = mtile * 128;
  const int tid = threadIdx.x;  // 0..511
  const int w = tid >> 6, l = tid & 63;
  const int lr = l & 15, lq = l >> 4;

  // staging: thread t -> A row r=t>>2, k-chunk c4=t&3 (8 consecutive floats).
  // dest = frag (mi=r>>4), frag-lane fl=(r&15)+16*c4 -> exactly the MFMA A-frag.
  const int r = tid >> 2, c4 = tid & 3;
  const float* gA = A + (size_t)(m0 + r) * 8192 + kseg * 1024 + c4 * 8;
  const int woff = (r >> 4) * 512 + ((r & 15) + 16 * c4) * 8;  // ushort index

  const unsigned short* Bbase = B2 + (size_t)kseg * 262144 + l * 8;

  f32x4 acc[8][2];
#pragma unroll
  for (int i = 0; i < 8; ++i)
#pragma unroll
    for (int j = 0; j < 2; ++j) acc[i][j] = (f32x4){0.f, 0.f, 0.f, 0.f};

  f32x4 saE0, saE1, saO0, saO1;  // two named A-staging sets (rule #20)
  bf16x8 Bf0, Bf1;

  auto loadA_E = [&](int h) {
    saE0 = *(const f32x4*)(gA + h * 32);
    saE1 = *(const f32x4*)(gA + h * 32 + 4);
  };
  auto loadA_O = [&](int h) {
    saO0 = *(const f32x4*)(gA + h * 32);
    saO1 = *(const f32x4*)(gA + h * 32 + 4);
  };
  auto writeA_E = [&](int h) {
    bf16x8 b;
    b[0] = (__bf16)saE0.x; b[1] = (__bf16)saE0.y; b[2] = (__bf16)saE0.z; b[3] = (__bf16)saE0.w;
    b[4] = (__bf16)saE1.x; b[5] = (__bf16)saE1.y; b[6] = (__bf16)saE1.z; b[7] = (__bf16)saE1.w;
    *(bf16x8*)(&Al[h & 1][woff]) = b;
  };
  auto writeA_O = [&](int h) {
    bf16x8 b;
    b[0] = (__bf16)saO0.x; b[1] = (__bf16)saO0.y; b[2] = (__bf16)saO0.z; b[3] = (__bf16)saO0.w;
    b[4] = (__bf16)saO1.x; b[5] = (__bf16)saO1.y; b[6] = (__bf16)saO1.z; b[7] = (__bf16)saO1.w;
    *(bf16x8*)(&Al[h & 1][woff]) = b;
  };
  auto loadB = [&](int h) {  // iter h: c=h>>1, kk=h&1; wave w = wp
    const unsigned short* p = Bbase + ((((h >> 1) * 8 + w) * 4 + (h & 1) * 2) << 9);
    Bf0 = *(const bf16x8*)(p);
    Bf1 = *(const bf16x8*)(p + 512);
  };
  auto compute = [&](int h) {
    const unsigned short* Ab = &Al[h & 1][0];
#pragma unroll
    for (int mi = 0; mi < 8; ++mi) {
      bf16x8 af = *(const bf16x8*)(Ab + mi * 512 + l * 8);  // lane-linear
      acc[mi][0] = __builtin_amdgcn_mfma_f32_16x16x32_bf16(af, Bf0, acc[mi][0], 0, 0, 0);
      acc[mi][1] = __builtin_amdgcn_mfma_f32_16x16x32_bf16(af, Bf1, acc[mi][1], 0, 0, 0);
    }
  };

  // prologue: A(0) staged+written (saE); A(1)->saO, A(2)->saE, B(0) in flight
  loadA_E(0);
  writeA_E(0);     // waits vmcnt for saE, cvt, ds_write buf0
  loadB(0);
  loadA_O(1);
  loadA_E(2);
  asm volatile("s_waitcnt lgkmcnt(0)" ::: "memory");
  asm volatile("s_barrier" ::: "memory");

  // 2-period bodies, h = 0,2,...,28 (periods 0..29); A in flight: h+1,h+2 (+h+3)
  for (int h = 0; h < 30; h += 2) {
    // period h (even; compute buf0, fill buf1 from saO)
    loadB(h + 1);                       // issue-early
    if (h + 3 <= 31) loadA_O(h + 3);    // wait: saO(h+1) must land first? no --
    // NOTE: loadA_O targets saO which still holds A(h+1) -> must write first.
    // So the order below keeps writeA_O BEFORE the next loadA_O. See body:
    compute(h);                          // vmcnt-wait on Bf(h); lgkm on ds_read
    writeA_O(h + 1);                     // vmcnt-wait on saO(h+1); ds_write buf1
    asm volatile("s_waitcnt lgkmcnt(0)" ::: "memory");
    asm volatile("s_barrier" ::: "memory");

    // period h+1 (odd; compute buf1, fill buf0 from saE)
    loadB(h + 2);
    if (h + 4 <= 31) loadA_E(h + 4);
    compute(h + 1);
    writeA_E(h + 2);
    asm volatile("s_waitcnt lgkmcnt(0)" ::: "memory");
    asm volatile("s_barrier" ::: "memory");
  }
  // tail: periods 30, 31. After loop: buf0 has A(30), buf1 has A(31)? --
  // loop last body h=28: wrote A(29)->buf1, A(30)->buf0; loaded A(31)->saO
  // (h+3=31 at h=28), saE load skipped (h+4=32).
  loadB(31);
  compute(30);                           // buf0
  writeA_O(31);                          // buf1
  asm volatile("s_waitcnt lgkmcnt(0)" ::: "memory");
  asm volatile("s_barrier" ::: "memory");
  compute(31);                           // buf1

  // epilogue: bf16 partial P[kseg][m][n]
  unsigned short* Pb = P + (size_t)kseg * (8192 * 256);
#pragma unroll
  for (int mi = 0; mi < 8; ++mi)
#pragma unroll
    for (int ni = 0; ni < 2; ++ni) {
      f32x4 z = acc[mi][ni];
      int n = w * 32 + ni * 16 + lr;
#pragma unroll
      for (int i = 0; i < 4; ++i) {
        int m = m0 + mi * 16 + lq * 4 + i;
        Pb[(size_t)m * 256 + n] = f2bf_bits(z[i]);
      }
    }
}

// ---------------- finalize8: out = x + s*(relu(sum P) - x) -------------------------
__global__ __launch_bounds__(256) void finalize8(
    const unsigned short* __restrict__ P,   // [8][8192][256] bf16
    const float* __restrict__ X,
    const float* __restrict__ s,
    float* __restrict__ out) {
  int i = blockIdx.x * 256 + threadIdx.x;  // 0..262143, 8 n-values each
  int m = i >> 5;
  float acc[8] = {0.f, 0.f, 0.f, 0.f, 0.f, 0.f, 0.f, 0.f};
#pragma unroll
  for (int ks = 0; ks < 8; ++ks) {
    u16x8 v = *(const u16x8*)(P + (size_t)ks * 2097152 + (size_t)i * 8);
#pragma unroll
    for (int j = 0; j < 8; ++j) acc[j] += bf2f(v[j]);
  }
  float sv = s[m];
  f32x4 x0 = *(const f32x4*)(X + (size_t)i * 8);
  f32x4 x1 = *(const f32x4*)(X + (size_t)i * 8 + 4);
  f32x4 o0, o1;
#pragma unroll
  for (int j = 0; j < 4; ++j) {
    o0[j] = x0[j] + sv * (fmaxf(acc[j], 0.f) - x0[j]);
    o1[j] = x1[j] + sv * (fmaxf(acc[4 + j], 0.f) - x1[j]);
  }
  *(f32x4*)(out + (size_t)i * 8) = o0;
  *(f32x4*)(out + (size_t)i * 8 + 4) = o1;
}

// ================= fallback path (round-6 kernels, unchanged) ======================
template <int NT, bool SPLIT>
__global__ __launch_bounds__(512, 4) void gemm_main(
    const float* __restrict__ A,
    const unsigned short* __restrict__ B2,
    const float* __restrict__ X,
    const float* __restrict__ s,
    float* __restrict__ out,
    float* __restrict__ P) {
  __shared__ float As[4][32 * 64];

  const int bid = blockIdx.x;
  const int m0 = SPLIT ? (bid >> 1) * 32 : bid * 32;
  const int khalf = SPLIT ? (bid & 1) : 0;
  const int tid = threadIdx.x;
  const int w = tid >> 6;
  const int l = tid & 63;
  const int lr = l & 15;
  const int lq = l >> 4;

  const int rA = tid >> 4;
  const int qA = tid & 15;
  const int sqA = qA ^ (rA & 15);
  const char* Asrc =
      (const char*)A + (size_t)(m0 + rA) * 32768 + (size_t)khalf * 16384 + sqA * 16;
  const char* Bbase =
      (const char*)B2 + (size_t)khalf * 64 * 32768 + (size_t)w * 4096 + (size_t)l * 16;

  f32x4 acc[2][2];
#pragma unroll
  for (int i = 0; i < 2; ++i)
#pragma unroll
    for (int j = 0; j < 2; ++j) acc[i][j] = (f32x4){0.f, 0.f, 0.f, 0.f};

  struct BF { bf16x8 a, b, c, d; };
  BF Bf0, Bf1;

  auto stageA = [&](int h, int buf) {
    gload16_stream(Asrc + (size_t)h * 256, (char*)&As[buf][0] + w * 1024);
  };
  auto loadB = [&](int h, BF& f) {
    const char* p = Bbase + (size_t)h * 32768;
    f.a = *(const bf16x8*)(p);
    f.b = *(const bf16x8*)(p + 1024);
    f.c = *(const bf16x8*)(p + 2048);
    f.d = *(const bf16x8*)(p + 3072);
  };

  auto compute = [&](int buf, const BF& f) {
    const char* Ab = (const char*)&As[buf][0];
    bf16x8 af[2][2];
#pragma unroll
    for (int kk = 0; kk < 2; ++kk)
#pragma unroll
      for (int mi = 0; mi < 2; ++mi) {
        int rr = mi * 16 + lr;
        int s0 = (kk * 8 + 2 * lq) ^ (rr & 15);
        int s1 = ((kk * 8 + 2 * lq) + 1) ^ (rr & 15);
        f32x4 a0 = *(const f32x4*)(Ab + rr * 256 + s0 * 16);
        f32x4 a1 = *(const f32x4*)(Ab + rr * 256 + s1 * 16);
        bf16x8 v;
        v[0] = (__bf16)a0.x; v[1] = (__bf16)a0.y; v[2] = (__bf16)a0.z; v[3] = (__bf16)a0.w;
        v[4] = (__bf16)a1.x; v[5] = (__bf16)a1.y; v[6] = (__bf16)a1.z; v[7] = (__bf16)a1.w;
        af[kk][mi] = v;
      }
    acc[0][0] = __builtin_amdgcn_mfma_f32_16x16x32_bf16(af[0][0], f.a, acc[0][0], 0, 0, 0);
    acc[0][1] = __builtin_amdgcn_mfma_f32_16x16x32_bf16(af[0][0], f.b, acc[0][1], 0, 0, 0);
    acc[1][0] = __builtin_amdgcn_mfma_f32_16x16x32_bf16(af[0][1], f.a, acc[1][0], 0, 0, 0);
    acc[1][1] = __builtin_amdgcn_mfma_f32_16x16x32_bf16(af[0][1], f.b, acc[1][1], 0, 0, 0);
    acc[0][0] = __builtin_amdgcn_mfma_f32_16x16x32_bf16(af[1][0], f.c, acc[0][0], 0, 0, 0);
    acc[0][1] = __builtin_amdgcn_mfma_f32_16x16x32_bf16(af[1][0], f.d, acc[0][1], 0, 0, 0);
    acc[1][0] = __builtin_amdgcn_mfma_f32_16x16x32_bf16(af[1][1], f.c, acc[1][0], 0, 0, 0);
    acc[1][1] = __builtin_amdgcn_mfma_f32_16x16x32_bf16(af[1][1], f.d, acc[1][1], 0, 0, 0);
  };

  stageA(0, 0);
  loadB(0, Bf0);
  stageA(1, 1);
  loadB(1, Bf1);
  stageA(2, 2);
  stageA(3, 3);

  for (int h = 0; h < NT - 4; h += 2) {
    asm volatile("s_waitcnt vmcnt(6)" ::: "memory");
    asm volatile("s_barrier" ::: "memory");
    compute(h & 3, Bf0);
    asm volatile("s_waitcnt lgkmcnt(0)" ::: "memory");
    asm volatile("s_barrier" ::: "memory");
    loadB(h + 2, Bf0);
    stageA(h + 4, h & 3);

    asm volatile("s_waitcnt vmcnt(6)" ::: "memory");
    asm volatile("s_barrier" ::: "memory");
    compute((h + 1) & 3, Bf1);
    asm volatile("s_waitcnt lgkmcnt(0)" ::: "memory");
    asm volatile("s_barrier" ::: "memory");
    loadB(h + 3, Bf1);
    stageA(h + 5, (h + 1) & 3);
  }
  asm volatile("s_waitcnt vmcnt(6)" ::: "memory");
  asm volatile("s_barrier" ::: "memory");
  compute(0, Bf0);
  asm volatile("s_waitcnt lgkmcnt(0)" ::: "memory");
  asm volatile("s_barrier" ::: "memory");
  loadB(NT - 2, Bf0);

  asm volatile("s_waitcnt vmcnt(5)" ::: "memory");
  asm volatile("s_barrier" ::: "memory");
  compute(1, Bf1);
  asm volatile("s_waitcnt lgkmcnt(0)" ::: "memory");
  asm volatile("s_barrier" ::: "memory");
  loadB(NT - 1, Bf1);

  asm volatile("s_waitcnt vmcnt(4)" ::: "memory");
  asm volatile("s_barrier" ::: "memory");
  compute(2, Bf0);
  asm volatile("s_waitcnt lgkmcnt(0)" ::: "memory");
  asm volatile("s_barrier" ::: "memory");

  asm volatile("s_waitcnt vmcnt(0)" ::: "memory");
  asm volatile("s_barrier" ::: "memory");
  compute(3, Bf1);

  if (SPLIT) {
    float* Pb = P + (size_t)khalf * 8192 * 256;
#pragma unroll
    for (int mi = 0; mi < 2; ++mi)
#pragma unroll
      for (int ni = 0; ni < 2; ++ni) {
        f32x4 z = acc[mi][ni];
        int n = w * 32 + ni * 16 + lr;
#pragma unroll
        for (int i = 0; i < 4; ++i) {
          int m = m0 + mi * 16 + lq * 4 + i;
          Pb[m * 256 + n] = z[i];
        }
      }
  } else {
#pragma unroll
    for (int mi = 0; mi < 2; ++mi)
#pragma unroll
      for (int ni = 0; ni < 2; ++ni) {
        f32x4 z = acc[mi][ni];
        int n = w * 32 + ni * 16 + lr;
#pragma unroll
        for (int i = 0; i < 4; ++i) {
          int m = m0 + mi * 16 + lq * 4 + i;
          float x = X[m * 256 + n];
          float sv = s[m];
          out[m * 256 + n] = x + sv * (fmaxf(z[i], 0.f) - x);
        }
      }
  }
}

__global__ __launch_bounds__(256) void finalize_kernel(
    const float* __restrict__ P,
    const float* __restrict__ X,
    const float* __restrict__ s,
    float* __restrict__ out) {
  int i = blockIdx.x * 256 + threadIdx.x;
  int m = i >> 6;
  f32x4 p0 = *(const f32x4*)(P + (size_t)i * 4);
  f32x4 p1 = *(const f32x4*)(P + 2097152 + (size_t)i * 4);
  f32x4 x = *(const f32x4*)(X + (size_t)i * 4);
  float sv = s[m];
  f32x4 o;
#pragma unroll
  for (int j = 0; j < 4; ++j) o[j] = x[j] + sv * (fmaxf(p0[j] + p1[j], 0.f) - x[j]);
  *(f32x4*)(out + (size_t)i * 4) = o;
}

extern "C" void kernel_launch(void* const* d_in, const int* in_sizes, int n_in,
                              void* d_out, int out_size, void* d_ws, size_t ws_size,
                              hipStream_t stream) {
  const float* X = (const float*)d_in[0];
  const float* A = (const float*)d_in[1];
  const float* wg = (const float*)d_in[2];
  const float* wl = (const float*)d_in[3];
  const float* W = (const float*)d_in[4];
  float* out = (float*)d_out;

  // ws: XWT2 4 MiB | WT 128 KiB | s 32 KiB | P (bf16 32 MiB new / f32 16 MiB old)
  unsigned short* XWT2 = (unsigned short*)d_ws;
  unsigned short* WT = (unsigned short*)((char*)d_ws + 4194304);
  float* s = (float*)((char*)d_ws + 4194304 + 131072);
  char* Pbase = (char*)d_ws + 4194304 + 131072 + 32768;

  prep_kernel<<<256, 256, 0, stream>>>(W, wg, wl, WT, s);
  gemm_xw<<<512, 256, 0, stream>>>(X, WT, XWT2);

  const size_t head = 4194304 + 131072 + 32768;
  const size_t need8 = head + (size_t)8 * 8192 * 256 * 2;   // bf16 partials
  const size_t need2 = head + (size_t)2 * 8192 * 256 * 4;   // f32 partials
  if (ws_size >= need8) {
    gemm_ks8<<<512, 512, 0, stream>>>(A, XWT2, (unsigned short*)Pbase);
    finalize8<<<1024, 256, 0, stream>>>((const unsigned short*)Pbase, X, s, out);
  } else if (ws_size >= need2) {
    gemm_main<64, true><<<512, 512, 0, stream>>>(A, XWT2, X, s, out, (float*)Pbase);
    finalize_kernel<<<2048, 256, 0, stream>>>((const float*)Pbase, X, s, out);
  } else {
    gemm_main<128, false><<<256, 512, 0, stream>>>(A, XWT2, X, s, out, nullptr);
  }
}